// Round 1
// 234.061 us; speedup vs baseline: 1.0405x; 1.0405x over previous
//
#include <hip/hip_runtime.h>

// SpMM: out[i,d] = sum_{e: rows[e]==i} vals[e] * x[cols[e], d]
// N=100000 nodes, E=1600000 edges, DIM=32, fp32.
//
// v2: bin-by-row then gather.
//  Previous (atomic) version: 51.2M fp32 atomicAdds -> WRITE_SIZE was exactly
//  51.2M*4B = 204.8 MB (atomics write through to the coherent point), 16x the
//  ideal 12.8 MB output. This version replaces them with 1.6M int atomics
//  (bin positions) + register accumulation + plain coalesced stores.
//
//  ws layout: [counts: N int][bins: N*C int2 {col, bitcast(val)}]
//  C=32 per-row capacity; degree is Poisson(16) so P(deg>32) ~ 1e-4 per row.
//  Overflow edges (rare) fall back to direct fp32 atomics into out; gather
//  then does += instead of = for those rows.

#define N_NODES 100000
#define N_EDGES 1600000
#define DIM 32

// ---------- fallback: previous verified kernel (thread per (edge,dim)) ----------
__global__ __launch_bounds__(256) void spmm_atomic_kernel(
    const int* __restrict__ rows,
    const int* __restrict__ cols,
    const float* __restrict__ vals,
    const float* __restrict__ x,
    float* __restrict__ out)
{
    const long long idx = (long long)blockIdx.x * blockDim.x + threadIdx.x;
    const long long total = (long long)N_EDGES * DIM;
    if (idx >= total) return;

    const int e = (int)(idx >> 5);
    const int d = (int)(idx & 31);

    const int r   = rows[e];
    const int c   = cols[e];
    const float v = vals[e];

    const float xv = x[(long long)c * DIM + d];
    atomicAdd(&out[(long long)r * DIM + d], v * xv);
}

// ---------- fast path ----------
__global__ __launch_bounds__(256) void spmm_scatter_bins(
    const int* __restrict__ rows,
    const int* __restrict__ cols,
    const float* __restrict__ vals,
    const float* __restrict__ x,
    int* __restrict__ counts,
    int2* __restrict__ bins,
    float* __restrict__ out,
    int C)
{
    const int e = blockIdx.x * blockDim.x + threadIdx.x;
    if (e >= N_EDGES) return;

    const int r   = rows[e];
    const int c   = cols[e];
    const float v = vals[e];

    const int pos = atomicAdd(&counts[r], 1);
    if (pos < C) {
        bins[r * C + pos] = make_int2(c, __float_as_int(v));
    } else {
        // rare overflow (Poisson(16) tail beyond C): direct atomic accumulate
        const float* __restrict__ xr = x + c * DIM;
        float* orow = out + r * DIM;
        #pragma unroll
        for (int d = 0; d < DIM; ++d)
            atomicAdd(&orow[d], v * xr[d]);
    }
}

__global__ __launch_bounds__(256) void spmm_gather_kernel(
    const int* __restrict__ counts,
    const int2* __restrict__ bins,
    const float* __restrict__ x,
    float* __restrict__ out,
    int C)
{
    // 256 threads = 8 rows x 32 dims; lane d = dim, 32-lane group per row.
    const int d = threadIdx.x & 31;
    const int r = (blockIdx.x << 3) + (threadIdx.x >> 5);
    if (r >= N_NODES) return;

    const int cnt = counts[r];
    const int n   = cnt < C ? cnt : C;
    const int2* __restrict__ b = bins + r * C;

    float acc = 0.f;
    int k = 0;
    // unroll 4: batch the bin broadcasts and x gathers for load-level parallelism
    for (; k + 3 < n; k += 4) {
        const int2 e0 = b[k + 0];
        const int2 e1 = b[k + 1];
        const int2 e2 = b[k + 2];
        const int2 e3 = b[k + 3];
        const float x0 = x[e0.x * DIM + d];
        const float x1 = x[e1.x * DIM + d];
        const float x2 = x[e2.x * DIM + d];
        const float x3 = x[e3.x * DIM + d];
        acc = fmaf(__int_as_float(e0.y), x0, acc);
        acc = fmaf(__int_as_float(e1.y), x1, acc);
        acc = fmaf(__int_as_float(e2.y), x2, acc);
        acc = fmaf(__int_as_float(e3.y), x3, acc);
    }
    for (; k < n; ++k) {
        const int2 e0 = b[k];
        acc = fmaf(__int_as_float(e0.y), x[e0.x * DIM + d], acc);
    }

    float* orow = out + r * DIM;
    if (cnt > C)
        orow[d] += acc;   // overflow contributions already atomically added
    else
        orow[d] = acc;    // out was zeroed; plain coalesced store
}

extern "C" void kernel_launch(void* const* d_in, const int* in_sizes, int n_in,
                              void* d_out, int out_size, void* d_ws, size_t ws_size,
                              hipStream_t stream) {
    const int*   A_rows = (const int*)d_in[0];
    const int*   A_cols = (const int*)d_in[1];
    const float* A_vals = (const float*)d_in[2];
    const float* x      = (const float*)d_in[3];
    float*       out    = (float*)d_out;

    // d_out is poisoned with 0xAA before every timed launch — zero it.
    hipMemsetAsync(out, 0, (size_t)out_size * sizeof(float), stream);

    const size_t counts_bytes = (size_t)N_NODES * sizeof(int);  // 400000, 8B-aligned
    int C = 0;
    if (d_ws != nullptr) {
        if (counts_bytes + (size_t)N_NODES * 32 * sizeof(int2) <= ws_size)      C = 32;
        else if (counts_bytes + (size_t)N_NODES * 24 * sizeof(int2) <= ws_size) C = 24;
    }

    if (C == 0) {
        // workspace too small: previous verified atomic path
        const long long total = (long long)N_EDGES * DIM;
        const int block = 256;
        const long long grid = (total + block - 1) / block;
        spmm_atomic_kernel<<<(dim3)(unsigned)grid, block, 0, stream>>>(
            A_rows, A_cols, A_vals, x, out);
        return;
    }

    int*  counts = (int*)d_ws;
    int2* bins   = (int2*)((char*)d_ws + counts_bytes);

    hipMemsetAsync(counts, 0, counts_bytes, stream);

    const int block = 256;
    spmm_scatter_bins<<<(N_EDGES + block - 1) / block, block, 0, stream>>>(
        A_rows, A_cols, A_vals, x, counts, bins, out, C);

    // 8 rows per 256-thread block
    spmm_gather_kernel<<<(N_NODES + 7) / 8, block, 0, stream>>>(
        counts, bins, x, out, C);
}